// Round 10
// baseline (262.031 us; speedup 1.0000x reference)
//
#include <hip/hip_runtime.h>
#include <hip/hip_bf16.h>

// ---------------------------------------------------------------------------
// GraphSAGE 2-layer, bf16-MFMA edition.
//   h   = relu( mean_nbr(x) @ W1l + x @ W1r + b1 )     (aggregate-first)
//   out = mean_nbr(h @ W2l) + h @ W2r + b2             (transform-first)
// R9 post-mortem: all kernels <40us (top-5 = harness poison fills). fused12
// model says BW floor ~10us vs ~35 actual; limiter = 3 blocks/CU (52KB LDS).
// R10: W1/W2 B-frags from global (L2-resident, m97-style k-loop), ws2 LDS
// dropped -> 34.8KB LDS + VGPR<=64 (launch_bounds 512,8) -> 4 blocks/CU.
// ---------------------------------------------------------------------------

#define FDIM 128
#define CDIM 32
#define SCAN_CHUNK 1024
#define PSTR 136        // padded LDS row stride in shorts (272B): 2-way bank
                        // aliasing for 16-row frag reads = free (m136)

typedef __attribute__((ext_vector_type(8))) short short8;
typedef __attribute__((ext_vector_type(4))) float f32x4;
typedef unsigned short ushort_t;
typedef unsigned int uint_t;

static __device__ __forceinline__ ushort_t f2bf(float f) {
    uint_t u = __float_as_uint(f);
    u += 0x7fffu + ((u >> 16) & 1u);       // round-to-nearest-even
    return (ushort_t)(u >> 16);
}
static __device__ __forceinline__ float bf2f_lo(uint_t u) {
    return __uint_as_float(u << 16);
}
static __device__ __forceinline__ float bf2f_hi(uint_t u) {
    return __uint_as_float(u & 0xffff0000u);
}

// ---- deg: 600k scattered device-scope atomics -----------------------------

__global__ void deg_kernel(const int* __restrict__ dst, int* __restrict__ deg,
                           int E, int n) {
    int e = blockIdx.x * 256 + threadIdx.x;
    if (e < E) {
        int d = dst[e];
        if (d >= 0 && d < n) atomicAdd(&deg[d], 1);
    }
}

// ---- prep: x->bf16 (blocks [0,CB)) | W transpose+cvt (blocks [CB,..)) -----

__global__ __launch_bounds__(256) void prep_kernel(
        const float* __restrict__ x, uint_t* __restrict__ xb4, long long total8,
        const float* __restrict__ W1l, const float* __restrict__ W1r,
        const float* __restrict__ W2l, const float* __restrict__ W2r,
        ushort_t* __restrict__ w1lt, ushort_t* __restrict__ w1rt,
        ushort_t* __restrict__ w2lt, ushort_t* __restrict__ w2rt,
        int CB) {
    int b = (int)blockIdx.x;
    if (b < CB) {
        long long i = (long long)b * 256 + threadIdx.x;
        if (i >= total8) return;
        const float4* p = (const float4*)x + i * 2;
        float4 v0 = p[0], v1 = p[1];
        uint4 o;
        o.x = (uint_t)f2bf(v0.x) | ((uint_t)f2bf(v0.y) << 16);
        o.y = (uint_t)f2bf(v0.z) | ((uint_t)f2bf(v0.w) << 16);
        o.z = (uint_t)f2bf(v1.x) | ((uint_t)f2bf(v1.y) << 16);
        o.w = (uint_t)f2bf(v1.z) | ((uint_t)f2bf(v1.w) << 16);
        ((uint4*)xb4)[i] = o;
    } else {
        int idx = (b - CB) * 256 + threadIdx.x;
        const float* w; ushort_t* wt; int Nc, local;
        if (idx < 16384)      { w = W1l; wt = w1lt; Nc = 128; local = idx; }
        else if (idx < 32768) { w = W1r; wt = w1rt; Nc = 128; local = idx - 16384; }
        else if (idx < 36864) { w = W2l; wt = w2lt; Nc = 32;  local = idx - 32768; }
        else if (idx < 40960) { w = W2r; wt = w2rt; Nc = 32;  local = idx - 36864; }
        else return;
        int nn = local >> 7, kk = local & 127;
        wt[nn * 128 + kk] = f2bf(w[kk * Nc + nn]);
    }
}

// ---- hierarchical scan (scan3 re-derives its block offset from partials) --

__global__ __launch_bounds__(256) void scan1_kernel(
        const int* __restrict__ deg, int* __restrict__ partials, int n) {
    __shared__ int red[256];
    int t = threadIdx.x;
    int base = blockIdx.x * SCAN_CHUNK + t * 4;
    int s = 0;
    if (base + 3 < n) {
        int4 v = *(const int4*)(deg + base);
        s = v.x + v.y + v.z + v.w;
    } else {
        for (int i = 0; i < 4; i++) if (base + i < n) s += deg[base + i];
    }
    red[t] = s;
    __syncthreads();
#pragma unroll
    for (int off = 128; off > 0; off >>= 1) {
        if (t < off) red[t] += red[t + off];
        __syncthreads();
    }
    if (t == 0) partials[blockIdx.x] = red[0];
}

__global__ __launch_bounds__(256) void scan3_kernel(
        const int* __restrict__ deg, const int* __restrict__ partials,
        int* __restrict__ rowptr, int n, int SB) {
    __shared__ int s[256];
    int t = threadIdx.x;
    int pre = (t < SB && t < (int)blockIdx.x) ? partials[t] : 0;
    s[t] = pre;
    __syncthreads();
#pragma unroll
    for (int off = 128; off > 0; off >>= 1) {
        if (t < off) s[t] += s[t + off];
        __syncthreads();
    }
    int blockbase = s[0];
    __syncthreads();

    int base = blockIdx.x * SCAN_CHUNK + t * 4;
    int d0 = 0, d1 = 0, d2 = 0, d3 = 0;
    if (base + 3 < n) {
        int4 v = *(const int4*)(deg + base);
        d0 = v.x; d1 = v.y; d2 = v.z; d3 = v.w;
    } else {
        if (base + 0 < n) d0 = deg[base + 0];
        if (base + 1 < n) d1 = deg[base + 1];
        if (base + 2 < n) d2 = deg[base + 2];
        if (base + 3 < n) d3 = deg[base + 3];
    }
    s[t] = d0 + d1 + d2 + d3;
    __syncthreads();
#pragma unroll
    for (int off = 1; off < 256; off <<= 1) {
        int u = (t >= off) ? s[t - off] : 0;
        __syncthreads();
        s[t] += u;
        __syncthreads();
    }
    int run = blockbase + ((t == 0) ? 0 : s[t - 1]);
    int dd[4] = {d0, d1, d2, d3};
#pragma unroll
    for (int i = 0; i < 4; i++) {
        if (base + i < n) {
            rowptr[base + i] = run;
            run += dd[i];
        }
    }
}

__global__ void fill_kernel(const int* __restrict__ src, const int* __restrict__ dst,
                            const int* __restrict__ rowptr, int* __restrict__ cursor,
                            int* __restrict__ nbr, int E, int n) {
    int e = blockIdx.x * 256 + threadIdx.x;
    if (e < E) {
        int s = src[e];
        int d = dst[e];
        if (d >= 0 && d < n) {
            int p = atomicAdd(&cursor[d], 1);
            nbr[rowptr[d] + p] = s;
        }
    }
}

// ---- agg1: aggb[i] = bf16( mean_{j in N(i)} xb[j] ) -----------------------
// One wave per node; 4 groups of 16 lanes; 2-deep edge prefetch per group.

__global__ __launch_bounds__(256) void agg1_kernel(
        const uint_t* __restrict__ xbu /* N x 64 uints */,
        const int* __restrict__ rowptr, const int* __restrict__ deg,
        const int* __restrict__ nbr, uint_t* __restrict__ aggbu, int n) {
    int t = threadIdx.x;
    int i = blockIdx.x * 4 + (t >> 6);
    if (i >= n) return;
    int lane = t & 63;
    int g    = lane >> 4;
    int l16  = lane & 15;
    int start = rowptr[i];
    int d     = deg[i];
    float s[8] = {0.f, 0.f, 0.f, 0.f, 0.f, 0.f, 0.f, 0.f};
    int e = g;
    for (; e + 4 < d; e += 8) {
        int j0 = nbr[start + e];
        int j1 = nbr[start + e + 4];
        uint4 u0 = *(const uint4*)(xbu + (size_t)j0 * 64 + l16 * 4);
        uint4 u1 = *(const uint4*)(xbu + (size_t)j1 * 64 + l16 * 4);
        s[0] += bf2f_lo(u0.x) + bf2f_lo(u1.x); s[1] += bf2f_hi(u0.x) + bf2f_hi(u1.x);
        s[2] += bf2f_lo(u0.y) + bf2f_lo(u1.y); s[3] += bf2f_hi(u0.y) + bf2f_hi(u1.y);
        s[4] += bf2f_lo(u0.z) + bf2f_lo(u1.z); s[5] += bf2f_hi(u0.z) + bf2f_hi(u1.z);
        s[6] += bf2f_lo(u0.w) + bf2f_lo(u1.w); s[7] += bf2f_hi(u0.w) + bf2f_hi(u1.w);
    }
    if (e < d) {
        int j = nbr[start + e];
        uint4 u = *(const uint4*)(xbu + (size_t)j * 64 + l16 * 4);
        s[0] += bf2f_lo(u.x); s[1] += bf2f_hi(u.x);
        s[2] += bf2f_lo(u.y); s[3] += bf2f_hi(u.y);
        s[4] += bf2f_lo(u.z); s[5] += bf2f_hi(u.z);
        s[6] += bf2f_lo(u.w); s[7] += bf2f_hi(u.w);
    }
#pragma unroll
    for (int k = 0; k < 8; k++) {
        s[k] += __shfl_xor(s[k], 16, 64);
        s[k] += __shfl_xor(s[k], 32, 64);
    }
    if (g == 0) {
        float inv = 1.0f / (float)(d > 0 ? d : 1);
        uint4 o;
        o.x = (uint_t)f2bf(s[0] * inv) | ((uint_t)f2bf(s[1] * inv) << 16);
        o.y = (uint_t)f2bf(s[2] * inv) | ((uint_t)f2bf(s[3] * inv) << 16);
        o.z = (uint_t)f2bf(s[4] * inv) | ((uint_t)f2bf(s[5] * inv) << 16);
        o.w = (uint_t)f2bf(s[6] * inv) | ((uint_t)f2bf(s[7] * inv) << 16);
        *(uint4*)(aggbu + (size_t)i * 64 + l16 * 4) = o;
    }
}

// ---- fused12: layer-1 GEMM + epilogue + layer-2 GEMM ----------------------
// 512 thr = 8 waves; tile = 64 rows. xb/aggb tiles in LDS (34.8KB); W1/W2
// B-frags read from global (80KB total, L2-resident) inside the loops --
// m97-style k-loop. VGPR forced <=64 -> 4 blocks/CU (32 waves).

__global__ __launch_bounds__(512, 8) void fused12_kernel(
        const ushort_t* __restrict__ xb, const ushort_t* __restrict__ aggb,
        const ushort_t* __restrict__ w1lt, const ushort_t* __restrict__ w1rt,
        const ushort_t* __restrict__ w2lt, const ushort_t* __restrict__ w2rt,
        const float* __restrict__ b1,
        ushort_t* __restrict__ z2b, float* __restrict__ r2, int n) {
    __shared__ ushort_t xs[64 * PSTR];          // x tile; becomes hs after layer 1
    __shared__ ushort_t as_[64 * PSTR];         // agg tile

    const int t    = threadIdx.x;
    const int wave = t >> 6;            // 0..7
    const int lane = t & 63;
    const int quad = lane >> 4;
    const int l16  = lane & 15;
    const int row0 = blockIdx.x * 64;
    const int c1   = wave * 16;         // layer-1 col tile

    // stage xb + aggb tiles: 1024 16B chunks each, 2 per thread, coalesced
#pragma unroll
    for (int it = 0; it < 2; it++) {
        int c   = t + it * 512;
        int row = c >> 4, col = c & 15;
        int grow = row0 + row; if (grow >= n) grow = n - 1;   // clamp; stores guarded
        size_t goff = (size_t)grow * FDIM + col * 8;
        short8 vx = *(const short8*)(xb + goff);
        short8 va = *(const short8*)(aggb + goff);
        *(short8*)(xs  + row * PSTR + col * 8) = vx;
        *(short8*)(as_ + row * PSTR + col * 8) = va;
    }

    float b1c = b1[c1 + l16];
    __syncthreads();

    // ---- layer 1: A-frags from LDS, B-frags from global (L2-hot) ----
    f32x4 acc1[4];
#pragma unroll
    for (int r = 0; r < 4; r++) acc1[r] = (f32x4){0.f, 0.f, 0.f, 0.f};

#pragma unroll
    for (int k = 0; k < 4; k++) {
        size_t woff = (size_t)(c1 + l16) * FDIM + k * 32 + quad * 8;
        short8 bl1 = *(const short8*)(w1lt + woff);
        short8 br1 = *(const short8*)(w1rt + woff);
        short8 a1[4], a2[4];
#pragma unroll
        for (int r = 0; r < 4; r++) {
            int lro = (r * 16 + l16) * PSTR + k * 32 + quad * 8;
            a1[r] = *(const short8*)(as_ + lro);
            a2[r] = *(const short8*)(xs  + lro);
        }
#pragma unroll
        for (int r = 0; r < 4; r++) {
            acc1[r] = __builtin_amdgcn_mfma_f32_16x16x32_bf16(a1[r], bl1, acc1[r], 0, 0, 0);
            acc1[r] = __builtin_amdgcn_mfma_f32_16x16x32_bf16(a2[r], br1, acc1[r], 0, 0, 0);
        }
    }

    __syncthreads();          // all waves done reading xs before hs overwrite

    // epilogue -> hs (= xs). C/D: col = l16, row = quad*4 + reg.
    ushort_t* hs = xs;
#pragma unroll
    for (int r = 0; r < 4; r++)
#pragma unroll
        for (int reg = 0; reg < 4; reg++) {
            int lrow = r * 16 + quad * 4 + reg;
            float v = acc1[r][reg] + b1c;
            v = v > 0.f ? v : 0.f;
            hs[lrow * PSTR + c1 + l16] = f2bf(v);
        }

    __syncthreads();

    // ---- layer 2: A from LDS hs, W2 frags from global (L2-hot) ----
    const int rs = (wave >> 1) * 16;    // row sub-tile
    const int c2 = (wave & 1) * 16;     // col tile
    f32x4 a2l = (f32x4){0.f, 0.f, 0.f, 0.f};
    f32x4 a2r = (f32x4){0.f, 0.f, 0.f, 0.f};
#pragma unroll
    for (int k = 0; k < 4; k++) {
        size_t woff = (size_t)(c2 + l16) * FDIM + k * 32 + quad * 8;
        short8 wl = *(const short8*)(w2lt + woff);
        short8 wr = *(const short8*)(w2rt + woff);
        short8 ah = *(const short8*)(hs + (rs + l16) * PSTR + k * 32 + quad * 8);
        a2l = __builtin_amdgcn_mfma_f32_16x16x32_bf16(ah, wl, a2l, 0, 0, 0);
        a2r = __builtin_amdgcn_mfma_f32_16x16x32_bf16(ah, wr, a2r, 0, 0, 0);
    }
#pragma unroll
    for (int reg = 0; reg < 4; reg++) {
        int grow = row0 + rs + quad * 4 + reg;
        if (grow < n) {
            z2b[(size_t)grow * CDIM + c2 + l16] = f2bf(a2l[reg]);
            r2 [(size_t)grow * CDIM + c2 + l16] = a2r[reg];
        }
    }
}

// ---- combine2: out = inv * sum_j z2b[j] + r2 + b2 -------------------------
// Wave per node; 8 subgroups of 8 lanes each take an edge (8 in flight),
// 2-deep prefetch (16 outstanding); rows read as uint2 (8B x 8 lanes = 64B).

__global__ __launch_bounds__(256) void combine2_kernel(
        const uint_t* __restrict__ z2bu /* N x 16 uints */,
        const int* __restrict__ rowptr, const int* __restrict__ deg,
        const int* __restrict__ nbr, const float* __restrict__ b2,
        const float* __restrict__ r2, float* __restrict__ out, int n) {
    int t = threadIdx.x;
    int i = blockIdx.x * 4 + (t >> 6);
    if (i >= n) return;
    int lane = t & 63;
    int sub  = lane >> 3;               // 0..7 subgroup (edge slot)
    int l8   = lane & 7;                // col chunk: 4 bf16 = cols 4*l8..4*l8+3
    int start = rowptr[i];
    int d     = deg[i];
    float s0 = 0.f, s1 = 0.f, s2 = 0.f, s3 = 0.f;
    int e = sub;
    for (; e + 8 < d; e += 16) {
        int j0 = nbr[start + e];
        int j1 = nbr[start + e + 8];
        uint2 u0 = *(const uint2*)(z2bu + (size_t)j0 * 16 + l8 * 2);
        uint2 u1 = *(const uint2*)(z2bu + (size_t)j1 * 16 + l8 * 2);
        s0 += bf2f_lo(u0.x) + bf2f_lo(u1.x);
        s1 += bf2f_hi(u0.x) + bf2f_hi(u1.x);
        s2 += bf2f_lo(u0.y) + bf2f_lo(u1.y);
        s3 += bf2f_hi(u0.y) + bf2f_hi(u1.y);
    }
    if (e < d) {
        int j = nbr[start + e];
        uint2 u = *(const uint2*)(z2bu + (size_t)j * 16 + l8 * 2);
        s0 += bf2f_lo(u.x);
        s1 += bf2f_hi(u.x);
        s2 += bf2f_lo(u.y);
        s3 += bf2f_hi(u.y);
    }
    s0 += __shfl_xor(s0, 8, 64); s0 += __shfl_xor(s0, 16, 64); s0 += __shfl_xor(s0, 32, 64);
    s1 += __shfl_xor(s1, 8, 64); s1 += __shfl_xor(s1, 16, 64); s1 += __shfl_xor(s1, 32, 64);
    s2 += __shfl_xor(s2, 8, 64); s2 += __shfl_xor(s2, 16, 64); s2 += __shfl_xor(s2, 32, 64);
    s3 += __shfl_xor(s3, 8, 64); s3 += __shfl_xor(s3, 16, 64); s3 += __shfl_xor(s3, 32, 64);
    if (sub == 0) {
        float inv = 1.0f / (float)(d > 0 ? d : 1);
        float4 rr = *(const float4*)(r2 + (size_t)i * CDIM + l8 * 4);
        float4 bb = *(const float4*)(b2 + l8 * 4);
        float4 o;
        o.x = s0 * inv + rr.x + bb.x;
        o.y = s1 * inv + rr.y + bb.y;
        o.z = s2 * inv + rr.z + bb.z;
        o.w = s3 * inv + rr.w + bb.w;
        *(float4*)(out + (size_t)i * CDIM + l8 * 4) = o;
    }
}

// ---------------------------------------------------------------------------

extern "C" void kernel_launch(void* const* d_in, const int* in_sizes, int n_in,
                              void* d_out, int out_size, void* d_ws, size_t ws_size,
                              hipStream_t stream) {
    const float* x   = (const float*)d_in[0];
    const int*   ei  = (const int*)d_in[1];     // int64 in ref -> int32 here
    const float* W1l = (const float*)d_in[2];
    const float* b1  = (const float*)d_in[3];
    const float* W1r = (const float*)d_in[4];
    const float* W2l = (const float*)d_in[5];
    const float* b2  = (const float*)d_in[6];
    const float* W2r = (const float*)d_in[7];

    const int N = in_sizes[0] / FDIM;
    const int E = in_sizes[1] / 2;
    const int* src = ei;
    const int* dst = ei + E;

    char* p = (char*)d_ws;
    int*      deg      = (int*)p;      p += (size_t)N * sizeof(int);
    int*      cursor   = (int*)p;      p += (size_t)N * sizeof(int);
    int*      rowptr   = (int*)p;      p += (size_t)N * sizeof(int);
    int*      partials = (int*)p;      p += 256 * sizeof(int);
    ushort_t* w1lt     = (ushort_t*)p; p += FDIM * FDIM * sizeof(ushort_t);
    ushort_t* w1rt     = (ushort_t*)p; p += FDIM * FDIM * sizeof(ushort_t);
    ushort_t* w2lt     = (ushort_t*)p; p += FDIM * CDIM * sizeof(ushort_t);
    ushort_t* w2rt     = (ushort_t*)p; p += FDIM * CDIM * sizeof(ushort_t);
    int*      nbr      = (int*)p;      p += (size_t)((E + 3) / 4 * 4) * sizeof(int);
    ushort_t* xb       = (ushort_t*)p; p += (size_t)N * FDIM * sizeof(ushort_t);
    ushort_t* aggb     = (ushort_t*)p; p += (size_t)N * FDIM * sizeof(ushort_t);
    ushort_t* z2b      = (ushort_t*)p; p += (size_t)N * CDIM * sizeof(ushort_t);
    float*    r2       = (float*)p;    p += (size_t)N * CDIM * sizeof(float);

    const int SB = (N + SCAN_CHUNK - 1) / SCAN_CHUNK;
    const long long total8 = (long long)N * FDIM / 8;
    const int CB = (int)((total8 + 255) / 256);
    const int DB = (E + 255) / 256;
    const int WB = (40960 + 255) / 256;

    hipMemsetAsync(deg, 0, 2 * (size_t)N * sizeof(int), stream);  // deg+cursor adjacent

    prep_kernel <<<CB + WB, 256, 0, stream>>>(x, (uint_t*)xb, total8,
                                              W1l, W1r, W2l, W2r,
                                              w1lt, w1rt, w2lt, w2rt, CB);
    deg_kernel  <<<DB, 256, 0, stream>>>(dst, deg, E, N);
    scan1_kernel<<<SB, 256, 0, stream>>>(deg, partials, N);
    scan3_kernel<<<SB, 256, 0, stream>>>(deg, partials, rowptr, N, SB);
    fill_kernel <<<DB, 256, 0, stream>>>(src, dst, rowptr, cursor, nbr, E, N);

    agg1_kernel   <<<(N + 3) / 4, 256, 0, stream>>>((const uint_t*)xb, rowptr, deg, nbr,
                                                    (uint_t*)aggb, N);
    fused12_kernel<<<(N + 63) / 64, 512, 0, stream>>>(xb, aggb, w1lt, w1rt, w2lt, w2rt,
                                                      b1, z2b, r2, N);
    combine2_kernel<<<(N + 3) / 4, 256, 0, stream>>>((const uint_t*)z2b, rowptr, deg, nbr,
                                                     b2, r2, (float*)d_out, N);
}

// Round 11
// 251.399 us; speedup vs baseline: 1.0423x; 1.0423x over previous
//
#include <hip/hip_runtime.h>
#include <hip/hip_bf16.h>

// ---------------------------------------------------------------------------
// GraphSAGE 2-layer, bf16-MFMA edition.
//   h   = relu( mean_nbr(x) @ W1l + x @ W1r + b1 )     (aggregate-first)
//   out = mean_nbr(h @ W2l) + h @ W2r + b2             (transform-first)
// R10 post-mortem: global-W fused12 regressed (-12us) -> reverted to R9 LDS
// version. fill measured 39.4us @ VALUBusy 0.5%: per-edge latency chain
// (atomic -> rowptr load -> store). R11: cursor pre-seeded with rowptr in
// scan3 (fill chain 2 deps -> 1) and deg/fill batch 4 edges/thread (int4).
// ---------------------------------------------------------------------------

#define FDIM 128
#define CDIM 32
#define SCAN_CHUNK 1024
#define PSTR 136        // padded LDS row stride in shorts (272B): 2-way bank
                        // aliasing for 16-row frag reads = free (m136)

typedef __attribute__((ext_vector_type(8))) short short8;
typedef __attribute__((ext_vector_type(4))) float f32x4;
typedef unsigned short ushort_t;
typedef unsigned int uint_t;

static __device__ __forceinline__ ushort_t f2bf(float f) {
    uint_t u = __float_as_uint(f);
    u += 0x7fffu + ((u >> 16) & 1u);       // round-to-nearest-even
    return (ushort_t)(u >> 16);
}
static __device__ __forceinline__ float bf2f_lo(uint_t u) {
    return __uint_as_float(u << 16);
}
static __device__ __forceinline__ float bf2f_hi(uint_t u) {
    return __uint_as_float(u & 0xffff0000u);
}

// ---- deg: 4 edges/thread, 4 independent atomics in flight -----------------

__global__ void deg_kernel(const int* __restrict__ dst, int* __restrict__ deg,
                           int E, int n) {
    int e0 = (blockIdx.x * 256 + threadIdx.x) * 4;
    if (e0 + 3 < E) {
        int4 d4 = *(const int4*)(dst + e0);
        if (d4.x >= 0 && d4.x < n) atomicAdd(&deg[d4.x], 1);
        if (d4.y >= 0 && d4.y < n) atomicAdd(&deg[d4.y], 1);
        if (d4.z >= 0 && d4.z < n) atomicAdd(&deg[d4.z], 1);
        if (d4.w >= 0 && d4.w < n) atomicAdd(&deg[d4.w], 1);
    } else {
        for (int e = e0; e < E; e++) {
            int d = dst[e];
            if (d >= 0 && d < n) atomicAdd(&deg[d], 1);
        }
    }
}

// ---- prep: x->bf16 (blocks [0,CB)) | W transpose+cvt (blocks [CB,..)) -----

__global__ __launch_bounds__(256) void prep_kernel(
        const float* __restrict__ x, uint_t* __restrict__ xb4, long long total8,
        const float* __restrict__ W1l, const float* __restrict__ W1r,
        const float* __restrict__ W2l, const float* __restrict__ W2r,
        ushort_t* __restrict__ w1lt, ushort_t* __restrict__ w1rt,
        ushort_t* __restrict__ w2lt, ushort_t* __restrict__ w2rt,
        int CB) {
    int b = (int)blockIdx.x;
    if (b < CB) {
        long long i = (long long)b * 256 + threadIdx.x;
        if (i >= total8) return;
        const float4* p = (const float4*)x + i * 2;
        float4 v0 = p[0], v1 = p[1];
        uint4 o;
        o.x = (uint_t)f2bf(v0.x) | ((uint_t)f2bf(v0.y) << 16);
        o.y = (uint_t)f2bf(v0.z) | ((uint_t)f2bf(v0.w) << 16);
        o.z = (uint_t)f2bf(v1.x) | ((uint_t)f2bf(v1.y) << 16);
        o.w = (uint_t)f2bf(v1.z) | ((uint_t)f2bf(v1.w) << 16);
        ((uint4*)xb4)[i] = o;
    } else {
        int idx = (b - CB) * 256 + threadIdx.x;
        const float* w; ushort_t* wt; int Nc, local;
        if (idx < 16384)      { w = W1l; wt = w1lt; Nc = 128; local = idx; }
        else if (idx < 32768) { w = W1r; wt = w1rt; Nc = 128; local = idx - 16384; }
        else if (idx < 36864) { w = W2l; wt = w2lt; Nc = 32;  local = idx - 32768; }
        else if (idx < 40960) { w = W2r; wt = w2rt; Nc = 32;  local = idx - 36864; }
        else return;
        int nn = local >> 7, kk = local & 127;
        wt[nn * 128 + kk] = f2bf(w[kk * Nc + nn]);
    }
}

// ---- hierarchical scan (scan3 re-derives its block offset from partials) --

__global__ __launch_bounds__(256) void scan1_kernel(
        const int* __restrict__ deg, int* __restrict__ partials, int n) {
    __shared__ int red[256];
    int t = threadIdx.x;
    int base = blockIdx.x * SCAN_CHUNK + t * 4;
    int s = 0;
    if (base + 3 < n) {
        int4 v = *(const int4*)(deg + base);
        s = v.x + v.y + v.z + v.w;
    } else {
        for (int i = 0; i < 4; i++) if (base + i < n) s += deg[base + i];
    }
    red[t] = s;
    __syncthreads();
#pragma unroll
    for (int off = 128; off > 0; off >>= 1) {
        if (t < off) red[t] += red[t + off];
        __syncthreads();
    }
    if (t == 0) partials[blockIdx.x] = red[0];
}

// also seeds cursor[i] = rowptr[i] so fill needs no rowptr load
__global__ __launch_bounds__(256) void scan3_kernel(
        const int* __restrict__ deg, const int* __restrict__ partials,
        int* __restrict__ rowptr, int* __restrict__ cursor, int n, int SB) {
    __shared__ int s[256];
    int t = threadIdx.x;
    int pre = (t < SB && t < (int)blockIdx.x) ? partials[t] : 0;
    s[t] = pre;
    __syncthreads();
#pragma unroll
    for (int off = 128; off > 0; off >>= 1) {
        if (t < off) s[t] += s[t + off];
        __syncthreads();
    }
    int blockbase = s[0];
    __syncthreads();

    int base = blockIdx.x * SCAN_CHUNK + t * 4;
    int d0 = 0, d1 = 0, d2 = 0, d3 = 0;
    if (base + 3 < n) {
        int4 v = *(const int4*)(deg + base);
        d0 = v.x; d1 = v.y; d2 = v.z; d3 = v.w;
    } else {
        if (base + 0 < n) d0 = deg[base + 0];
        if (base + 1 < n) d1 = deg[base + 1];
        if (base + 2 < n) d2 = deg[base + 2];
        if (base + 3 < n) d3 = deg[base + 3];
    }
    s[t] = d0 + d1 + d2 + d3;
    __syncthreads();
#pragma unroll
    for (int off = 1; off < 256; off <<= 1) {
        int u = (t >= off) ? s[t - off] : 0;
        __syncthreads();
        s[t] += u;
        __syncthreads();
    }
    int run = blockbase + ((t == 0) ? 0 : s[t - 1]);
    int dd[4] = {d0, d1, d2, d3};
#pragma unroll
    for (int i = 0; i < 4; i++) {
        if (base + i < n) {
            rowptr[base + i] = run;
            cursor[base + i] = run;
            run += dd[i];
        }
    }
}

// ---- fill: 4 edges/thread; cursor pre-seeded with rowptr ------------------

__global__ void fill_kernel(const int* __restrict__ src, const int* __restrict__ dst,
                            int* __restrict__ cursor, int* __restrict__ nbr,
                            int E, int n) {
    int e0 = (blockIdx.x * 256 + threadIdx.x) * 4;
    if (e0 + 3 < E) {
        int4 s4 = *(const int4*)(src + e0);
        int4 d4 = *(const int4*)(dst + e0);
        if (d4.x >= 0 && d4.x < n) { int p = atomicAdd(&cursor[d4.x], 1); nbr[p] = s4.x; }
        if (d4.y >= 0 && d4.y < n) { int p = atomicAdd(&cursor[d4.y], 1); nbr[p] = s4.y; }
        if (d4.z >= 0 && d4.z < n) { int p = atomicAdd(&cursor[d4.z], 1); nbr[p] = s4.z; }
        if (d4.w >= 0 && d4.w < n) { int p = atomicAdd(&cursor[d4.w], 1); nbr[p] = s4.w; }
    } else {
        for (int e = e0; e < E; e++) {
            int d = dst[e];
            if (d >= 0 && d < n) { int p = atomicAdd(&cursor[d], 1); nbr[p] = src[e]; }
        }
    }
}

// ---- agg1: aggb[i] = bf16( mean_{j in N(i)} xb[j] ) -----------------------
// One wave per node; 4 groups of 16 lanes; 2-deep edge prefetch per group.

__global__ __launch_bounds__(256) void agg1_kernel(
        const uint_t* __restrict__ xbu /* N x 64 uints */,
        const int* __restrict__ rowptr, const int* __restrict__ deg,
        const int* __restrict__ nbr, uint_t* __restrict__ aggbu, int n) {
    int t = threadIdx.x;
    int i = blockIdx.x * 4 + (t >> 6);
    if (i >= n) return;
    int lane = t & 63;
    int g    = lane >> 4;
    int l16  = lane & 15;
    int start = rowptr[i];
    int d     = deg[i];
    float s[8] = {0.f, 0.f, 0.f, 0.f, 0.f, 0.f, 0.f, 0.f};
    int e = g;
    for (; e + 4 < d; e += 8) {
        int j0 = nbr[start + e];
        int j1 = nbr[start + e + 4];
        uint4 u0 = *(const uint4*)(xbu + (size_t)j0 * 64 + l16 * 4);
        uint4 u1 = *(const uint4*)(xbu + (size_t)j1 * 64 + l16 * 4);
        s[0] += bf2f_lo(u0.x) + bf2f_lo(u1.x); s[1] += bf2f_hi(u0.x) + bf2f_hi(u1.x);
        s[2] += bf2f_lo(u0.y) + bf2f_lo(u1.y); s[3] += bf2f_hi(u0.y) + bf2f_hi(u1.y);
        s[4] += bf2f_lo(u0.z) + bf2f_lo(u1.z); s[5] += bf2f_hi(u0.z) + bf2f_hi(u1.z);
        s[6] += bf2f_lo(u0.w) + bf2f_lo(u1.w); s[7] += bf2f_hi(u0.w) + bf2f_hi(u1.w);
    }
    if (e < d) {
        int j = nbr[start + e];
        uint4 u = *(const uint4*)(xbu + (size_t)j * 64 + l16 * 4);
        s[0] += bf2f_lo(u.x); s[1] += bf2f_hi(u.x);
        s[2] += bf2f_lo(u.y); s[3] += bf2f_hi(u.y);
        s[4] += bf2f_lo(u.z); s[5] += bf2f_hi(u.z);
        s[6] += bf2f_lo(u.w); s[7] += bf2f_hi(u.w);
    }
#pragma unroll
    for (int k = 0; k < 8; k++) {
        s[k] += __shfl_xor(s[k], 16, 64);
        s[k] += __shfl_xor(s[k], 32, 64);
    }
    if (g == 0) {
        float inv = 1.0f / (float)(d > 0 ? d : 1);
        uint4 o;
        o.x = (uint_t)f2bf(s[0] * inv) | ((uint_t)f2bf(s[1] * inv) << 16);
        o.y = (uint_t)f2bf(s[2] * inv) | ((uint_t)f2bf(s[3] * inv) << 16);
        o.z = (uint_t)f2bf(s[4] * inv) | ((uint_t)f2bf(s[5] * inv) << 16);
        o.w = (uint_t)f2bf(s[6] * inv) | ((uint_t)f2bf(s[7] * inv) << 16);
        *(uint4*)(aggbu + (size_t)i * 64 + l16 * 4) = o;
    }
}

// ---- fused12: layer-1 GEMM + epilogue + layer-2 GEMM, LDS-tiled (R9) ------
// 512 thr = 8 waves; tile = 64 rows; 52KB LDS -> 3 blocks/CU.

__global__ __launch_bounds__(512, 6) void fused12_kernel(
        const ushort_t* __restrict__ xb, const ushort_t* __restrict__ aggb,
        const ushort_t* __restrict__ w1lt, const ushort_t* __restrict__ w1rt,
        const ushort_t* __restrict__ w2lt, const ushort_t* __restrict__ w2rt,
        const float* __restrict__ b1,
        ushort_t* __restrict__ z2b, float* __restrict__ r2, int n) {
    __shared__ ushort_t xs[64 * PSTR];          // x tile; becomes hs after layer 1
    __shared__ ushort_t as_[64 * PSTR];         // agg tile
    __shared__ ushort_t ws2[2 * 32 * PSTR];     // W2l^T | W2r^T

    const int t    = threadIdx.x;
    const int wave = t >> 6;            // 0..7
    const int lane = t & 63;
    const int quad = lane >> 4;
    const int l16  = lane & 15;
    const int row0 = blockIdx.x * 64;
    const int c1   = wave * 16;         // layer-1 col tile

    // stage xb + aggb tiles: 1024 16B chunks each, 2 per thread, coalesced
#pragma unroll
    for (int it = 0; it < 2; it++) {
        int c   = t + it * 512;
        int row = c >> 4, col = c & 15;
        int grow = row0 + row; if (grow >= n) grow = n - 1;   // clamp; stores guarded
        size_t goff = (size_t)grow * FDIM + col * 8;
        short8 vx = *(const short8*)(xb + goff);
        short8 va = *(const short8*)(aggb + goff);
        *(short8*)(xs  + row * PSTR + col * 8) = vx;
        *(short8*)(as_ + row * PSTR + col * 8) = va;
    }
    // stage W2 (both 32x128): 1024 chunks, 2 per thread
#pragma unroll
    for (int it = 0; it < 2; it++) {
        int c = t + it * 512;
        int m = c >> 9, lo = c & 511;
        int row = lo >> 4, col = lo & 15;
        const ushort_t* sw = m ? w2rt : w2lt;
        *(short8*)(ws2 + (m * 32 + row) * PSTR + col * 8) =
            *(const short8*)(sw + row * 128 + col * 8);
    }

    // W1 B-frags for this wave's 16 cols -> registers (L2-resident)
    short8 bl1[4], br1[4];
#pragma unroll
    for (int k = 0; k < 4; k++) {
        size_t woff = (size_t)(c1 + l16) * FDIM + k * 32 + quad * 8;
        bl1[k] = *(const short8*)(w1lt + woff);
        br1[k] = *(const short8*)(w1rt + woff);
    }
    float b1c = b1[c1 + l16];

    __syncthreads();

    // ---- layer 1: A-frags from LDS ----
    f32x4 acc1[4];
#pragma unroll
    for (int r = 0; r < 4; r++) acc1[r] = (f32x4){0.f, 0.f, 0.f, 0.f};

#pragma unroll
    for (int k = 0; k < 4; k++) {
        short8 a1[4], a2[4];
#pragma unroll
        for (int r = 0; r < 4; r++) {
            int lro = (r * 16 + l16) * PSTR + k * 32 + quad * 8;
            a1[r] = *(const short8*)(as_ + lro);
            a2[r] = *(const short8*)(xs  + lro);
        }
#pragma unroll
        for (int r = 0; r < 4; r++) {
            acc1[r] = __builtin_amdgcn_mfma_f32_16x16x32_bf16(a1[r], bl1[k], acc1[r], 0, 0, 0);
            acc1[r] = __builtin_amdgcn_mfma_f32_16x16x32_bf16(a2[r], br1[k], acc1[r], 0, 0, 0);
        }
    }

    __syncthreads();          // all waves done reading xs before hs overwrite

    // epilogue -> hs (= xs). C/D: col = l16, row = quad*4 + reg.
    ushort_t* hs = xs;
#pragma unroll
    for (int r = 0; r < 4; r++)
#pragma unroll
        for (int reg = 0; reg < 4; reg++) {
            int lrow = r * 16 + quad * 4 + reg;
            float v = acc1[r][reg] + b1c;
            v = v > 0.f ? v : 0.f;
            hs[lrow * PSTR + c1 + l16] = f2bf(v);
        }

    __syncthreads();

    // ---- layer 2 ----
    const int rs = (wave >> 1) * 16;    // row sub-tile
    const int c2 = (wave & 1) * 16;     // col tile
    f32x4 a2l = (f32x4){0.f, 0.f, 0.f, 0.f};
    f32x4 a2r = (f32x4){0.f, 0.f, 0.f, 0.f};
#pragma unroll
    for (int k = 0; k < 4; k++) {
        short8 ah = *(const short8*)(hs  + (rs + l16) * PSTR + k * 32 + quad * 8);
        short8 wl = *(const short8*)(ws2 + (c2 + l16) * PSTR + k * 32 + quad * 8);
        short8 wr = *(const short8*)(ws2 + (32 + c2 + l16) * PSTR + k * 32 + quad * 8);
        a2l = __builtin_amdgcn_mfma_f32_16x16x32_bf16(ah, wl, a2l, 0, 0, 0);
        a2r = __builtin_amdgcn_mfma_f32_16x16x32_bf16(ah, wr, a2r, 0, 0, 0);
    }
#pragma unroll
    for (int reg = 0; reg < 4; reg++) {
        int grow = row0 + rs + quad * 4 + reg;
        if (grow < n) {
            z2b[(size_t)grow * CDIM + c2 + l16] = f2bf(a2l[reg]);
            r2 [(size_t)grow * CDIM + c2 + l16] = a2r[reg];
        }
    }
}

// ---- combine2: out = inv * sum_j z2b[j] + r2 + b2 -------------------------
// Wave per node; 8 subgroups of 8 lanes each take an edge (8 in flight),
// 2-deep prefetch (16 outstanding); rows read as uint2 (8B x 8 lanes = 64B).

__global__ __launch_bounds__(256) void combine2_kernel(
        const uint_t* __restrict__ z2bu /* N x 16 uints */,
        const int* __restrict__ rowptr, const int* __restrict__ deg,
        const int* __restrict__ nbr, const float* __restrict__ b2,
        const float* __restrict__ r2, float* __restrict__ out, int n) {
    int t = threadIdx.x;
    int i = blockIdx.x * 4 + (t >> 6);
    if (i >= n) return;
    int lane = t & 63;
    int sub  = lane >> 3;               // 0..7 subgroup (edge slot)
    int l8   = lane & 7;                // col chunk: 4 bf16 = cols 4*l8..4*l8+3
    int start = rowptr[i];
    int d     = deg[i];
    float s0 = 0.f, s1 = 0.f, s2 = 0.f, s3 = 0.f;
    int e = sub;
    for (; e + 8 < d; e += 16) {
        int j0 = nbr[start + e];
        int j1 = nbr[start + e + 8];
        uint2 u0 = *(const uint2*)(z2bu + (size_t)j0 * 16 + l8 * 2);
        uint2 u1 = *(const uint2*)(z2bu + (size_t)j1 * 16 + l8 * 2);
        s0 += bf2f_lo(u0.x) + bf2f_lo(u1.x);
        s1 += bf2f_hi(u0.x) + bf2f_hi(u1.x);
        s2 += bf2f_lo(u0.y) + bf2f_lo(u1.y);
        s3 += bf2f_hi(u0.y) + bf2f_hi(u1.y);
    }
    if (e < d) {
        int j = nbr[start + e];
        uint2 u = *(const uint2*)(z2bu + (size_t)j * 16 + l8 * 2);
        s0 += bf2f_lo(u.x);
        s1 += bf2f_hi(u.x);
        s2 += bf2f_lo(u.y);
        s3 += bf2f_hi(u.y);
    }
    s0 += __shfl_xor(s0, 8, 64); s0 += __shfl_xor(s0, 16, 64); s0 += __shfl_xor(s0, 32, 64);
    s1 += __shfl_xor(s1, 8, 64); s1 += __shfl_xor(s1, 16, 64); s1 += __shfl_xor(s1, 32, 64);
    s2 += __shfl_xor(s2, 8, 64); s2 += __shfl_xor(s2, 16, 64); s2 += __shfl_xor(s2, 32, 64);
    s3 += __shfl_xor(s3, 8, 64); s3 += __shfl_xor(s3, 16, 64); s3 += __shfl_xor(s3, 32, 64);
    if (sub == 0) {
        float inv = 1.0f / (float)(d > 0 ? d : 1);
        float4 rr = *(const float4*)(r2 + (size_t)i * CDIM + l8 * 4);
        float4 bb = *(const float4*)(b2 + l8 * 4);
        float4 o;
        o.x = s0 * inv + rr.x + bb.x;
        o.y = s1 * inv + rr.y + bb.y;
        o.z = s2 * inv + rr.z + bb.z;
        o.w = s3 * inv + rr.w + bb.w;
        *(float4*)(out + (size_t)i * CDIM + l8 * 4) = o;
    }
}

// ---------------------------------------------------------------------------

extern "C" void kernel_launch(void* const* d_in, const int* in_sizes, int n_in,
                              void* d_out, int out_size, void* d_ws, size_t ws_size,
                              hipStream_t stream) {
    const float* x   = (const float*)d_in[0];
    const int*   ei  = (const int*)d_in[1];     // int64 in ref -> int32 here
    const float* W1l = (const float*)d_in[2];
    const float* b1  = (const float*)d_in[3];
    const float* W1r = (const float*)d_in[4];
    const float* W2l = (const float*)d_in[5];
    const float* b2  = (const float*)d_in[6];
    const float* W2r = (const float*)d_in[7];

    const int N = in_sizes[0] / FDIM;
    const int E = in_sizes[1] / 2;
    const int* src = ei;
    const int* dst = ei + E;

    char* p = (char*)d_ws;
    int*      deg      = (int*)p;      p += (size_t)N * sizeof(int);
    int*      cursor   = (int*)p;      p += (size_t)N * sizeof(int);
    int*      rowptr   = (int*)p;      p += (size_t)N * sizeof(int);
    int*      partials = (int*)p;      p += 256 * sizeof(int);
    ushort_t* w1lt     = (ushort_t*)p; p += FDIM * FDIM * sizeof(ushort_t);
    ushort_t* w1rt     = (ushort_t*)p; p += FDIM * FDIM * sizeof(ushort_t);
    ushort_t* w2lt     = (ushort_t*)p; p += FDIM * CDIM * sizeof(ushort_t);
    ushort_t* w2rt     = (ushort_t*)p; p += FDIM * CDIM * sizeof(ushort_t);
    int*      nbr      = (int*)p;      p += (size_t)((E + 3) / 4 * 4) * sizeof(int);
    ushort_t* xb       = (ushort_t*)p; p += (size_t)N * FDIM * sizeof(ushort_t);
    ushort_t* aggb     = (ushort_t*)p; p += (size_t)N * FDIM * sizeof(ushort_t);
    ushort_t* z2b      = (ushort_t*)p; p += (size_t)N * CDIM * sizeof(ushort_t);
    float*    r2       = (float*)p;    p += (size_t)N * CDIM * sizeof(float);

    const int SB = (N + SCAN_CHUNK - 1) / SCAN_CHUNK;
    const long long total8 = (long long)N * FDIM / 8;
    const int CB = (int)((total8 + 255) / 256);
    const int E4 = (E + 3) / 4;
    const int DB4 = (E4 + 255) / 256;
    const int WB = (40960 + 255) / 256;

    hipMemsetAsync(deg, 0, (size_t)N * sizeof(int), stream);  // cursor seeded by scan3

    prep_kernel <<<CB + WB, 256, 0, stream>>>(x, (uint_t*)xb, total8,
                                              W1l, W1r, W2l, W2r,
                                              w1lt, w1rt, w2lt, w2rt, CB);
    deg_kernel  <<<DB4, 256, 0, stream>>>(dst, deg, E, N);
    scan1_kernel<<<SB, 256, 0, stream>>>(deg, partials, N);
    scan3_kernel<<<SB, 256, 0, stream>>>(deg, partials, rowptr, cursor, N, SB);
    fill_kernel <<<DB4, 256, 0, stream>>>(src, dst, cursor, nbr, E, N);

    agg1_kernel   <<<(N + 3) / 4, 256, 0, stream>>>((const uint_t*)xb, rowptr, deg, nbr,
                                                    (uint_t*)aggb, N);
    fused12_kernel<<<(N + 63) / 64, 512, 0, stream>>>(xb, aggb, w1lt, w1rt, w2lt, w2rt,
                                                      b1, z2b, r2, N);
    combine2_kernel<<<(N + 3) / 4, 256, 0, stream>>>((const uint_t*)z2b, rowptr, deg, nbr,
                                                     b2, r2, (float*)d_out, N);
}

// Round 12
// 237.417 us; speedup vs baseline: 1.1037x; 1.0589x over previous
//
#include <hip/hip_runtime.h>
#include <hip/hip_bf16.h>

// ---------------------------------------------------------------------------
// GraphSAGE 2-layer, bf16-MFMA edition.
//   h   = relu( mean_nbr(x) @ W1l + x @ W1r + b1 )     (aggregate-first)
//   out = mean_nbr(h @ W2l) + h @ W2r + b2             (transform-first)
// R11 post-mortem: fill/deg fixes neutral; with mean deg~6 the edge loops
// are short -- gathers are bound by the per-node serial chain. R12: agg1 and
// combine2 restructured to ONE NODE PER 16-LANE GROUP (4 nodes/wave, 128
// chains/CU vs 32), lanes partition the row so no cross-lane reduce.
// ---------------------------------------------------------------------------

#define FDIM 128
#define CDIM 32
#define SCAN_CHUNK 1024
#define PSTR 136        // padded LDS row stride in shorts (272B): 2-way bank
                        // aliasing for 16-row frag reads = free (m136)

typedef __attribute__((ext_vector_type(8))) short short8;
typedef __attribute__((ext_vector_type(4))) float f32x4;
typedef unsigned short ushort_t;
typedef unsigned int uint_t;

static __device__ __forceinline__ ushort_t f2bf(float f) {
    uint_t u = __float_as_uint(f);
    u += 0x7fffu + ((u >> 16) & 1u);       // round-to-nearest-even
    return (ushort_t)(u >> 16);
}
static __device__ __forceinline__ float bf2f_lo(uint_t u) {
    return __uint_as_float(u << 16);
}
static __device__ __forceinline__ float bf2f_hi(uint_t u) {
    return __uint_as_float(u & 0xffff0000u);
}

// ---- deg: 4 edges/thread, 4 independent atomics in flight -----------------

__global__ void deg_kernel(const int* __restrict__ dst, int* __restrict__ deg,
                           int E, int n) {
    int e0 = (blockIdx.x * 256 + threadIdx.x) * 4;
    if (e0 + 3 < E) {
        int4 d4 = *(const int4*)(dst + e0);
        if (d4.x >= 0 && d4.x < n) atomicAdd(&deg[d4.x], 1);
        if (d4.y >= 0 && d4.y < n) atomicAdd(&deg[d4.y], 1);
        if (d4.z >= 0 && d4.z < n) atomicAdd(&deg[d4.z], 1);
        if (d4.w >= 0 && d4.w < n) atomicAdd(&deg[d4.w], 1);
    } else {
        for (int e = e0; e < E; e++) {
            int d = dst[e];
            if (d >= 0 && d < n) atomicAdd(&deg[d], 1);
        }
    }
}

// ---- prep: x->bf16 (blocks [0,CB)) | W transpose+cvt (blocks [CB,..)) -----

__global__ __launch_bounds__(256) void prep_kernel(
        const float* __restrict__ x, uint_t* __restrict__ xb4, long long total8,
        const float* __restrict__ W1l, const float* __restrict__ W1r,
        const float* __restrict__ W2l, const float* __restrict__ W2r,
        ushort_t* __restrict__ w1lt, ushort_t* __restrict__ w1rt,
        ushort_t* __restrict__ w2lt, ushort_t* __restrict__ w2rt,
        int CB) {
    int b = (int)blockIdx.x;
    if (b < CB) {
        long long i = (long long)b * 256 + threadIdx.x;
        if (i >= total8) return;
        const float4* p = (const float4*)x + i * 2;
        float4 v0 = p[0], v1 = p[1];
        uint4 o;
        o.x = (uint_t)f2bf(v0.x) | ((uint_t)f2bf(v0.y) << 16);
        o.y = (uint_t)f2bf(v0.z) | ((uint_t)f2bf(v0.w) << 16);
        o.z = (uint_t)f2bf(v1.x) | ((uint_t)f2bf(v1.y) << 16);
        o.w = (uint_t)f2bf(v1.z) | ((uint_t)f2bf(v1.w) << 16);
        ((uint4*)xb4)[i] = o;
    } else {
        int idx = (b - CB) * 256 + threadIdx.x;
        const float* w; ushort_t* wt; int Nc, local;
        if (idx < 16384)      { w = W1l; wt = w1lt; Nc = 128; local = idx; }
        else if (idx < 32768) { w = W1r; wt = w1rt; Nc = 128; local = idx - 16384; }
        else if (idx < 36864) { w = W2l; wt = w2lt; Nc = 32;  local = idx - 32768; }
        else if (idx < 40960) { w = W2r; wt = w2rt; Nc = 32;  local = idx - 36864; }
        else return;
        int nn = local >> 7, kk = local & 127;
        wt[nn * 128 + kk] = f2bf(w[kk * Nc + nn]);
    }
}

// ---- hierarchical scan (scan3 re-derives its block offset from partials) --

__global__ __launch_bounds__(256) void scan1_kernel(
        const int* __restrict__ deg, int* __restrict__ partials, int n) {
    __shared__ int red[256];
    int t = threadIdx.x;
    int base = blockIdx.x * SCAN_CHUNK + t * 4;
    int s = 0;
    if (base + 3 < n) {
        int4 v = *(const int4*)(deg + base);
        s = v.x + v.y + v.z + v.w;
    } else {
        for (int i = 0; i < 4; i++) if (base + i < n) s += deg[base + i];
    }
    red[t] = s;
    __syncthreads();
#pragma unroll
    for (int off = 128; off > 0; off >>= 1) {
        if (t < off) red[t] += red[t + off];
        __syncthreads();
    }
    if (t == 0) partials[blockIdx.x] = red[0];
}

// also seeds cursor[i] = rowptr[i] so fill needs no rowptr load
__global__ __launch_bounds__(256) void scan3_kernel(
        const int* __restrict__ deg, const int* __restrict__ partials,
        int* __restrict__ rowptr, int* __restrict__ cursor, int n, int SB) {
    __shared__ int s[256];
    int t = threadIdx.x;
    int pre = (t < SB && t < (int)blockIdx.x) ? partials[t] : 0;
    s[t] = pre;
    __syncthreads();
#pragma unroll
    for (int off = 128; off > 0; off >>= 1) {
        if (t < off) s[t] += s[t + off];
        __syncthreads();
    }
    int blockbase = s[0];
    __syncthreads();

    int base = blockIdx.x * SCAN_CHUNK + t * 4;
    int d0 = 0, d1 = 0, d2 = 0, d3 = 0;
    if (base + 3 < n) {
        int4 v = *(const int4*)(deg + base);
        d0 = v.x; d1 = v.y; d2 = v.z; d3 = v.w;
    } else {
        if (base + 0 < n) d0 = deg[base + 0];
        if (base + 1 < n) d1 = deg[base + 1];
        if (base + 2 < n) d2 = deg[base + 2];
        if (base + 3 < n) d3 = deg[base + 3];
    }
    s[t] = d0 + d1 + d2 + d3;
    __syncthreads();
#pragma unroll
    for (int off = 1; off < 256; off <<= 1) {
        int u = (t >= off) ? s[t - off] : 0;
        __syncthreads();
        s[t] += u;
        __syncthreads();
    }
    int run = blockbase + ((t == 0) ? 0 : s[t - 1]);
    int dd[4] = {d0, d1, d2, d3};
#pragma unroll
    for (int i = 0; i < 4; i++) {
        if (base + i < n) {
            rowptr[base + i] = run;
            cursor[base + i] = run;
            run += dd[i];
        }
    }
}

// ---- fill: 4 edges/thread; cursor pre-seeded with rowptr ------------------

__global__ void fill_kernel(const int* __restrict__ src, const int* __restrict__ dst,
                            int* __restrict__ cursor, int* __restrict__ nbr,
                            int E, int n) {
    int e0 = (blockIdx.x * 256 + threadIdx.x) * 4;
    if (e0 + 3 < E) {
        int4 s4 = *(const int4*)(src + e0);
        int4 d4 = *(const int4*)(dst + e0);
        if (d4.x >= 0 && d4.x < n) { int p = atomicAdd(&cursor[d4.x], 1); nbr[p] = s4.x; }
        if (d4.y >= 0 && d4.y < n) { int p = atomicAdd(&cursor[d4.y], 1); nbr[p] = s4.y; }
        if (d4.z >= 0 && d4.z < n) { int p = atomicAdd(&cursor[d4.z], 1); nbr[p] = s4.z; }
        if (d4.w >= 0 && d4.w < n) { int p = atomicAdd(&cursor[d4.w], 1); nbr[p] = s4.w; }
    } else {
        for (int e = e0; e < E; e++) {
            int d = dst[e];
            if (d >= 0 && d < n) { int p = atomicAdd(&cursor[d], 1); nbr[p] = src[e]; }
        }
    }
}

// ---- agg1: aggb[i] = bf16( mean_{j in N(i)} xb[j] ) -----------------------
// ONE NODE PER 16-LANE GROUP (4 nodes/wave): lanes partition the 256B row
// (uint4/lane), edges walked serially 2-deep -- no cross-lane reduce needed.
// 128 independent gather chains per CU (vs 32 with wave-per-node).

__global__ __launch_bounds__(256) void agg1_kernel(
        const uint_t* __restrict__ xbu /* N x 64 uints */,
        const int* __restrict__ rowptr, const int* __restrict__ deg,
        const int* __restrict__ nbr, uint_t* __restrict__ aggbu, int n) {
    int t = threadIdx.x;
    int i = blockIdx.x * 16 + (t >> 4);
    if (i >= n) return;
    int l16 = t & 15;
    int start = rowptr[i];
    int d     = deg[i];
    float s[8] = {0.f, 0.f, 0.f, 0.f, 0.f, 0.f, 0.f, 0.f};
    int e = 0;
    for (; e + 1 < d; e += 2) {
        int j0 = nbr[start + e];
        int j1 = nbr[start + e + 1];
        uint4 u0 = *(const uint4*)(xbu + (size_t)j0 * 64 + l16 * 4);
        uint4 u1 = *(const uint4*)(xbu + (size_t)j1 * 64 + l16 * 4);
        s[0] += bf2f_lo(u0.x) + bf2f_lo(u1.x); s[1] += bf2f_hi(u0.x) + bf2f_hi(u1.x);
        s[2] += bf2f_lo(u0.y) + bf2f_lo(u1.y); s[3] += bf2f_hi(u0.y) + bf2f_hi(u1.y);
        s[4] += bf2f_lo(u0.z) + bf2f_lo(u1.z); s[5] += bf2f_hi(u0.z) + bf2f_hi(u1.z);
        s[6] += bf2f_lo(u0.w) + bf2f_lo(u1.w); s[7] += bf2f_hi(u0.w) + bf2f_hi(u1.w);
    }
    if (e < d) {
        int j = nbr[start + e];
        uint4 u = *(const uint4*)(xbu + (size_t)j * 64 + l16 * 4);
        s[0] += bf2f_lo(u.x); s[1] += bf2f_hi(u.x);
        s[2] += bf2f_lo(u.y); s[3] += bf2f_hi(u.y);
        s[4] += bf2f_lo(u.z); s[5] += bf2f_hi(u.z);
        s[6] += bf2f_lo(u.w); s[7] += bf2f_hi(u.w);
    }
    float inv = 1.0f / (float)(d > 0 ? d : 1);
    uint4 o;
    o.x = (uint_t)f2bf(s[0] * inv) | ((uint_t)f2bf(s[1] * inv) << 16);
    o.y = (uint_t)f2bf(s[2] * inv) | ((uint_t)f2bf(s[3] * inv) << 16);
    o.z = (uint_t)f2bf(s[4] * inv) | ((uint_t)f2bf(s[5] * inv) << 16);
    o.w = (uint_t)f2bf(s[6] * inv) | ((uint_t)f2bf(s[7] * inv) << 16);
    *(uint4*)(aggbu + (size_t)i * 64 + l16 * 4) = o;
}

// ---- fused12: layer-1 GEMM + epilogue + layer-2 GEMM, LDS-tiled (R9) ------
// 512 thr = 8 waves; tile = 64 rows; 52KB LDS -> 3 blocks/CU.

__global__ __launch_bounds__(512, 6) void fused12_kernel(
        const ushort_t* __restrict__ xb, const ushort_t* __restrict__ aggb,
        const ushort_t* __restrict__ w1lt, const ushort_t* __restrict__ w1rt,
        const ushort_t* __restrict__ w2lt, const ushort_t* __restrict__ w2rt,
        const float* __restrict__ b1,
        ushort_t* __restrict__ z2b, float* __restrict__ r2, int n) {
    __shared__ ushort_t xs[64 * PSTR];          // x tile; becomes hs after layer 1
    __shared__ ushort_t as_[64 * PSTR];         // agg tile
    __shared__ ushort_t ws2[2 * 32 * PSTR];     // W2l^T | W2r^T

    const int t    = threadIdx.x;
    const int wave = t >> 6;            // 0..7
    const int lane = t & 63;
    const int quad = lane >> 4;
    const int l16  = lane & 15;
    const int row0 = blockIdx.x * 64;
    const int c1   = wave * 16;         // layer-1 col tile

    // stage xb + aggb tiles: 1024 16B chunks each, 2 per thread, coalesced
#pragma unroll
    for (int it = 0; it < 2; it++) {
        int c   = t + it * 512;
        int row = c >> 4, col = c & 15;
        int grow = row0 + row; if (grow >= n) grow = n - 1;   // clamp; stores guarded
        size_t goff = (size_t)grow * FDIM + col * 8;
        short8 vx = *(const short8*)(xb + goff);
        short8 va = *(const short8*)(aggb + goff);
        *(short8*)(xs  + row * PSTR + col * 8) = vx;
        *(short8*)(as_ + row * PSTR + col * 8) = va;
    }
    // stage W2 (both 32x128): 1024 chunks, 2 per thread
#pragma unroll
    for (int it = 0; it < 2; it++) {
        int c = t + it * 512;
        int m = c >> 9, lo = c & 511;
        int row = lo >> 4, col = lo & 15;
        const ushort_t* sw = m ? w2rt : w2lt;
        *(short8*)(ws2 + (m * 32 + row) * PSTR + col * 8) =
            *(const short8*)(sw + row * 128 + col * 8);
    }

    // W1 B-frags for this wave's 16 cols -> registers (L2-resident)
    short8 bl1[4], br1[4];
#pragma unroll
    for (int k = 0; k < 4; k++) {
        size_t woff = (size_t)(c1 + l16) * FDIM + k * 32 + quad * 8;
        bl1[k] = *(const short8*)(w1lt + woff);
        br1[k] = *(const short8*)(w1rt + woff);
    }
    float b1c = b1[c1 + l16];

    __syncthreads();

    // ---- layer 1: A-frags from LDS ----
    f32x4 acc1[4];
#pragma unroll
    for (int r = 0; r < 4; r++) acc1[r] = (f32x4){0.f, 0.f, 0.f, 0.f};

#pragma unroll
    for (int k = 0; k < 4; k++) {
        short8 a1[4], a2[4];
#pragma unroll
        for (int r = 0; r < 4; r++) {
            int lro = (r * 16 + l16) * PSTR + k * 32 + quad * 8;
            a1[r] = *(const short8*)(as_ + lro);
            a2[r] = *(const short8*)(xs  + lro);
        }
#pragma unroll
        for (int r = 0; r < 4; r++) {
            acc1[r] = __builtin_amdgcn_mfma_f32_16x16x32_bf16(a1[r], bl1[k], acc1[r], 0, 0, 0);
            acc1[r] = __builtin_amdgcn_mfma_f32_16x16x32_bf16(a2[r], br1[k], acc1[r], 0, 0, 0);
        }
    }

    __syncthreads();          // all waves done reading xs before hs overwrite

    // epilogue -> hs (= xs). C/D: col = l16, row = quad*4 + reg.
    ushort_t* hs = xs;
#pragma unroll
    for (int r = 0; r < 4; r++)
#pragma unroll
        for (int reg = 0; reg < 4; reg++) {
            int lrow = r * 16 + quad * 4 + reg;
            float v = acc1[r][reg] + b1c;
            v = v > 0.f ? v : 0.f;
            hs[lrow * PSTR + c1 + l16] = f2bf(v);
        }

    __syncthreads();

    // ---- layer 2 ----
    const int rs = (wave >> 1) * 16;    // row sub-tile
    const int c2 = (wave & 1) * 16;     // col tile
    f32x4 a2l = (f32x4){0.f, 0.f, 0.f, 0.f};
    f32x4 a2r = (f32x4){0.f, 0.f, 0.f, 0.f};
#pragma unroll
    for (int k = 0; k < 4; k++) {
        short8 ah = *(const short8*)(hs  + (rs + l16) * PSTR + k * 32 + quad * 8);
        short8 wl = *(const short8*)(ws2 + (c2 + l16) * PSTR + k * 32 + quad * 8);
        short8 wr = *(const short8*)(ws2 + (32 + c2 + l16) * PSTR + k * 32 + quad * 8);
        a2l = __builtin_amdgcn_mfma_f32_16x16x32_bf16(ah, wl, a2l, 0, 0, 0);
        a2r = __builtin_amdgcn_mfma_f32_16x16x32_bf16(ah, wr, a2r, 0, 0, 0);
    }
#pragma unroll
    for (int reg = 0; reg < 4; reg++) {
        int grow = row0 + rs + quad * 4 + reg;
        if (grow < n) {
            z2b[(size_t)grow * CDIM + c2 + l16] = f2bf(a2l[reg]);
            r2 [(size_t)grow * CDIM + c2 + l16] = a2r[reg];
        }
    }
}

// ---- combine2: out = inv * sum_j z2b[j] + r2 + b2 -------------------------
// ONE NODE PER 16-LANE GROUP: lanes partition the 64B row (uint/lane),
// serial 2-deep edge walk, no reduce; float2/lane epilogue.

__global__ __launch_bounds__(256) void combine2_kernel(
        const uint_t* __restrict__ z2bu /* N x 16 uints */,
        const int* __restrict__ rowptr, const int* __restrict__ deg,
        const int* __restrict__ nbr, const float* __restrict__ b2,
        const float* __restrict__ r2, float* __restrict__ out, int n) {
    int t = threadIdx.x;
    int i = blockIdx.x * 16 + (t >> 4);
    if (i >= n) return;
    int l16 = t & 15;
    int start = rowptr[i];
    int d     = deg[i];
    float s0 = 0.f, s1 = 0.f;
    int e = 0;
    for (; e + 1 < d; e += 2) {
        int j0 = nbr[start + e];
        int j1 = nbr[start + e + 1];
        uint_t u0 = z2bu[(size_t)j0 * 16 + l16];
        uint_t u1 = z2bu[(size_t)j1 * 16 + l16];
        s0 += bf2f_lo(u0) + bf2f_lo(u1);
        s1 += bf2f_hi(u0) + bf2f_hi(u1);
    }
    if (e < d) {
        int j = nbr[start + e];
        uint_t u = z2bu[(size_t)j * 16 + l16];
        s0 += bf2f_lo(u);
        s1 += bf2f_hi(u);
    }
    float inv = 1.0f / (float)(d > 0 ? d : 1);
    float2 rr = *(const float2*)(r2 + (size_t)i * CDIM + l16 * 2);
    float2 bb = *(const float2*)(b2 + l16 * 2);
    float2 o;
    o.x = s0 * inv + rr.x + bb.x;
    o.y = s1 * inv + rr.y + bb.y;
    *(float2*)(out + (size_t)i * CDIM + l16 * 2) = o;
}

// ---------------------------------------------------------------------------

extern "C" void kernel_launch(void* const* d_in, const int* in_sizes, int n_in,
                              void* d_out, int out_size, void* d_ws, size_t ws_size,
                              hipStream_t stream) {
    const float* x   = (const float*)d_in[0];
    const int*   ei  = (const int*)d_in[1];     // int64 in ref -> int32 here
    const float* W1l = (const float*)d_in[2];
    const float* b1  = (const float*)d_in[3];
    const float* W1r = (const float*)d_in[4];
    const float* W2l = (const float*)d_in[5];
    const float* b2  = (const float*)d_in[6];
    const float* W2r = (const float*)d_in[7];

    const int N = in_sizes[0] / FDIM;
    const int E = in_sizes[1] / 2;
    const int* src = ei;
    const int* dst = ei + E;

    char* p = (char*)d_ws;
    int*      deg      = (int*)p;      p += (size_t)N * sizeof(int);
    int*      cursor   = (int*)p;      p += (size_t)N * sizeof(int);
    int*      rowptr   = (int*)p;      p += (size_t)N * sizeof(int);
    int*      partials = (int*)p;      p += 256 * sizeof(int);
    ushort_t* w1lt     = (ushort_t*)p; p += FDIM * FDIM * sizeof(ushort_t);
    ushort_t* w1rt     = (ushort_t*)p; p += FDIM * FDIM * sizeof(ushort_t);
    ushort_t* w2lt     = (ushort_t*)p; p += FDIM * CDIM * sizeof(ushort_t);
    ushort_t* w2rt     = (ushort_t*)p; p += FDIM * CDIM * sizeof(ushort_t);
    int*      nbr      = (int*)p;      p += (size_t)((E + 3) / 4 * 4) * sizeof(int);
    ushort_t* xb       = (ushort_t*)p; p += (size_t)N * FDIM * sizeof(ushort_t);
    ushort_t* aggb     = (ushort_t*)p; p += (size_t)N * FDIM * sizeof(ushort_t);
    ushort_t* z2b      = (ushort_t*)p; p += (size_t)N * CDIM * sizeof(ushort_t);
    float*    r2       = (float*)p;    p += (size_t)N * CDIM * sizeof(float);

    const int SB = (N + SCAN_CHUNK - 1) / SCAN_CHUNK;
    const long long total8 = (long long)N * FDIM / 8;
    const int CB = (int)((total8 + 255) / 256);
    const int E4 = (E + 3) / 4;
    const int DB4 = (E4 + 255) / 256;
    const int WB = (40960 + 255) / 256;

    hipMemsetAsync(deg, 0, (size_t)N * sizeof(int), stream);  // cursor seeded by scan3

    prep_kernel <<<CB + WB, 256, 0, stream>>>(x, (uint_t*)xb, total8,
                                              W1l, W1r, W2l, W2r,
                                              w1lt, w1rt, w2lt, w2rt, CB);
    deg_kernel  <<<DB4, 256, 0, stream>>>(dst, deg, E, N);
    scan1_kernel<<<SB, 256, 0, stream>>>(deg, partials, N);
    scan3_kernel<<<SB, 256, 0, stream>>>(deg, partials, rowptr, cursor, N, SB);
    fill_kernel <<<DB4, 256, 0, stream>>>(src, dst, cursor, nbr, E, N);

    agg1_kernel   <<<(N + 15) / 16, 256, 0, stream>>>((const uint_t*)xb, rowptr, deg, nbr,
                                                      (uint_t*)aggb, N);
    fused12_kernel<<<(N + 63) / 64, 512, 0, stream>>>(xb, aggb, w1lt, w1rt, w2lt, w2rt,
                                                      b1, z2b, r2, N);
    combine2_kernel<<<(N + 15) / 16, 256, 0, stream>>>((const uint_t*)z2b, rowptr, deg, nbr,
                                                       b2, r2, (float*)d_out, N);
}

// Round 13
// 231.405 us; speedup vs baseline: 1.1323x; 1.0260x over previous
//
#include <hip/hip_runtime.h>
#include <hip/hip_bf16.h>

// ---------------------------------------------------------------------------
// GraphSAGE 2-layer, bf16-MFMA edition.
//   h   = relu( mean_nbr(x) @ W1l + x @ W1r + b1 )     (aggregate-first)
//   out = mean_nbr(h @ W2l) + h @ W2r + b2             (transform-first)
// R12 post-mortem: 16-lane-group gathers (128 chains/CU) won (-14us).
// R13: deg merged into prep as the FIRST block range -- its latency-bound
// scattered atomics co-schedule with (and hide under) the BW-bound x-cvt
// streaming blocks on other CUs, instead of running serially after them.
// ---------------------------------------------------------------------------

#define FDIM 128
#define CDIM 32
#define SCAN_CHUNK 1024
#define PSTR 136        // padded LDS row stride in shorts (272B): 2-way bank
                        // aliasing for 16-row frag reads = free (m136)

typedef __attribute__((ext_vector_type(8))) short short8;
typedef __attribute__((ext_vector_type(4))) float f32x4;
typedef unsigned short ushort_t;
typedef unsigned int uint_t;

static __device__ __forceinline__ ushort_t f2bf(float f) {
    uint_t u = __float_as_uint(f);
    u += 0x7fffu + ((u >> 16) & 1u);       // round-to-nearest-even
    return (ushort_t)(u >> 16);
}
static __device__ __forceinline__ float bf2f_lo(uint_t u) {
    return __uint_as_float(u << 16);
}
static __device__ __forceinline__ float bf2f_hi(uint_t u) {
    return __uint_as_float(u & 0xffff0000u);
}

// ---- prep: deg atomics (blocks [0,DB4)) | x->bf16 | W transpose+cvt -------
// deg range FIRST so its latency-bound blocks overlap the streaming ranges.

__global__ __launch_bounds__(256) void prep_kernel(
        const int* __restrict__ dst, int* __restrict__ deg, int E, int n,
        const float* __restrict__ x, uint_t* __restrict__ xb4, long long total8,
        const float* __restrict__ W1l, const float* __restrict__ W1r,
        const float* __restrict__ W2l, const float* __restrict__ W2r,
        ushort_t* __restrict__ w1lt, ushort_t* __restrict__ w1rt,
        ushort_t* __restrict__ w2lt, ushort_t* __restrict__ w2rt,
        int DB4, int CB) {
    int b = (int)blockIdx.x;
    if (b < DB4) {
        int e0 = (b * 256 + threadIdx.x) * 4;
        if (e0 + 3 < E) {
            int4 d4 = *(const int4*)(dst + e0);
            if (d4.x >= 0 && d4.x < n) atomicAdd(&deg[d4.x], 1);
            if (d4.y >= 0 && d4.y < n) atomicAdd(&deg[d4.y], 1);
            if (d4.z >= 0 && d4.z < n) atomicAdd(&deg[d4.z], 1);
            if (d4.w >= 0 && d4.w < n) atomicAdd(&deg[d4.w], 1);
        } else {
            for (int e = e0; e < E; e++) {
                int d = dst[e];
                if (d >= 0 && d < n) atomicAdd(&deg[d], 1);
            }
        }
    } else if (b < DB4 + CB) {
        long long i = (long long)(b - DB4) * 256 + threadIdx.x;
        if (i >= total8) return;
        const float4* p = (const float4*)x + i * 2;
        float4 v0 = p[0], v1 = p[1];
        uint4 o;
        o.x = (uint_t)f2bf(v0.x) | ((uint_t)f2bf(v0.y) << 16);
        o.y = (uint_t)f2bf(v0.z) | ((uint_t)f2bf(v0.w) << 16);
        o.z = (uint_t)f2bf(v1.x) | ((uint_t)f2bf(v1.y) << 16);
        o.w = (uint_t)f2bf(v1.z) | ((uint_t)f2bf(v1.w) << 16);
        ((uint4*)xb4)[i] = o;
    } else {
        int idx = (b - DB4 - CB) * 256 + threadIdx.x;
        const float* w; ushort_t* wt; int Nc, local;
        if (idx < 16384)      { w = W1l; wt = w1lt; Nc = 128; local = idx; }
        else if (idx < 32768) { w = W1r; wt = w1rt; Nc = 128; local = idx - 16384; }
        else if (idx < 36864) { w = W2l; wt = w2lt; Nc = 32;  local = idx - 32768; }
        else if (idx < 40960) { w = W2r; wt = w2rt; Nc = 32;  local = idx - 36864; }
        else return;
        int nn = local >> 7, kk = local & 127;
        wt[nn * 128 + kk] = f2bf(w[kk * Nc + nn]);
    }
}

// ---- hierarchical scan (scan3 re-derives its block offset from partials) --

__global__ __launch_bounds__(256) void scan1_kernel(
        const int* __restrict__ deg, int* __restrict__ partials, int n) {
    __shared__ int red[256];
    int t = threadIdx.x;
    int base = blockIdx.x * SCAN_CHUNK + t * 4;
    int s = 0;
    if (base + 3 < n) {
        int4 v = *(const int4*)(deg + base);
        s = v.x + v.y + v.z + v.w;
    } else {
        for (int i = 0; i < 4; i++) if (base + i < n) s += deg[base + i];
    }
    red[t] = s;
    __syncthreads();
#pragma unroll
    for (int off = 128; off > 0; off >>= 1) {
        if (t < off) red[t] += red[t + off];
        __syncthreads();
    }
    if (t == 0) partials[blockIdx.x] = red[0];
}

// also seeds cursor[i] = rowptr[i] so fill needs no rowptr load
__global__ __launch_bounds__(256) void scan3_kernel(
        const int* __restrict__ deg, const int* __restrict__ partials,
        int* __restrict__ rowptr, int* __restrict__ cursor, int n, int SB) {
    __shared__ int s[256];
    int t = threadIdx.x;
    int pre = (t < SB && t < (int)blockIdx.x) ? partials[t] : 0;
    s[t] = pre;
    __syncthreads();
#pragma unroll
    for (int off = 128; off > 0; off >>= 1) {
        if (t < off) s[t] += s[t + off];
        __syncthreads();
    }
    int blockbase = s[0];
    __syncthreads();

    int base = blockIdx.x * SCAN_CHUNK + t * 4;
    int d0 = 0, d1 = 0, d2 = 0, d3 = 0;
    if (base + 3 < n) {
        int4 v = *(const int4*)(deg + base);
        d0 = v.x; d1 = v.y; d2 = v.z; d3 = v.w;
    } else {
        if (base + 0 < n) d0 = deg[base + 0];
        if (base + 1 < n) d1 = deg[base + 1];
        if (base + 2 < n) d2 = deg[base + 2];
        if (base + 3 < n) d3 = deg[base + 3];
    }
    s[t] = d0 + d1 + d2 + d3;
    __syncthreads();
#pragma unroll
    for (int off = 1; off < 256; off <<= 1) {
        int u = (t >= off) ? s[t - off] : 0;
        __syncthreads();
        s[t] += u;
        __syncthreads();
    }
    int run = blockbase + ((t == 0) ? 0 : s[t - 1]);
    int dd[4] = {d0, d1, d2, d3};
#pragma unroll
    for (int i = 0; i < 4; i++) {
        if (base + i < n) {
            rowptr[base + i] = run;
            cursor[base + i] = run;
            run += dd[i];
        }
    }
}

// ---- fill: 4 edges/thread; cursor pre-seeded with rowptr ------------------

__global__ void fill_kernel(const int* __restrict__ src, const int* __restrict__ dst,
                            int* __restrict__ cursor, int* __restrict__ nbr,
                            int E, int n) {
    int e0 = (blockIdx.x * 256 + threadIdx.x) * 4;
    if (e0 + 3 < E) {
        int4 s4 = *(const int4*)(src + e0);
        int4 d4 = *(const int4*)(dst + e0);
        if (d4.x >= 0 && d4.x < n) { int p = atomicAdd(&cursor[d4.x], 1); nbr[p] = s4.x; }
        if (d4.y >= 0 && d4.y < n) { int p = atomicAdd(&cursor[d4.y], 1); nbr[p] = s4.y; }
        if (d4.z >= 0 && d4.z < n) { int p = atomicAdd(&cursor[d4.z], 1); nbr[p] = s4.z; }
        if (d4.w >= 0 && d4.w < n) { int p = atomicAdd(&cursor[d4.w], 1); nbr[p] = s4.w; }
    } else {
        for (int e = e0; e < E; e++) {
            int d = dst[e];
            if (d >= 0 && d < n) { int p = atomicAdd(&cursor[d], 1); nbr[p] = src[e]; }
        }
    }
}

// ---- agg1: aggb[i] = bf16( mean_{j in N(i)} xb[j] ) -----------------------
// ONE NODE PER 16-LANE GROUP (4 nodes/wave): lanes partition the 256B row
// (uint4/lane), edges walked serially 2-deep -- no cross-lane reduce needed.
// 128 independent gather chains per CU.

__global__ __launch_bounds__(256) void agg1_kernel(
        const uint_t* __restrict__ xbu /* N x 64 uints */,
        const int* __restrict__ rowptr, const int* __restrict__ deg,
        const int* __restrict__ nbr, uint_t* __restrict__ aggbu, int n) {
    int t = threadIdx.x;
    int i = blockIdx.x * 16 + (t >> 4);
    if (i >= n) return;
    int l16 = t & 15;
    int start = rowptr[i];
    int d     = deg[i];
    float s[8] = {0.f, 0.f, 0.f, 0.f, 0.f, 0.f, 0.f, 0.f};
    int e = 0;
    for (; e + 1 < d; e += 2) {
        int j0 = nbr[start + e];
        int j1 = nbr[start + e + 1];
        uint4 u0 = *(const uint4*)(xbu + (size_t)j0 * 64 + l16 * 4);
        uint4 u1 = *(const uint4*)(xbu + (size_t)j1 * 64 + l16 * 4);
        s[0] += bf2f_lo(u0.x) + bf2f_lo(u1.x); s[1] += bf2f_hi(u0.x) + bf2f_hi(u1.x);
        s[2] += bf2f_lo(u0.y) + bf2f_lo(u1.y); s[3] += bf2f_hi(u0.y) + bf2f_hi(u1.y);
        s[4] += bf2f_lo(u0.z) + bf2f_lo(u1.z); s[5] += bf2f_hi(u0.z) + bf2f_hi(u1.z);
        s[6] += bf2f_lo(u0.w) + bf2f_lo(u1.w); s[7] += bf2f_hi(u0.w) + bf2f_hi(u1.w);
    }
    if (e < d) {
        int j = nbr[start + e];
        uint4 u = *(const uint4*)(xbu + (size_t)j * 64 + l16 * 4);
        s[0] += bf2f_lo(u.x); s[1] += bf2f_hi(u.x);
        s[2] += bf2f_lo(u.y); s[3] += bf2f_hi(u.y);
        s[4] += bf2f_lo(u.z); s[5] += bf2f_hi(u.z);
        s[6] += bf2f_lo(u.w); s[7] += bf2f_hi(u.w);
    }
    float inv = 1.0f / (float)(d > 0 ? d : 1);
    uint4 o;
    o.x = (uint_t)f2bf(s[0] * inv) | ((uint_t)f2bf(s[1] * inv) << 16);
    o.y = (uint_t)f2bf(s[2] * inv) | ((uint_t)f2bf(s[3] * inv) << 16);
    o.z = (uint_t)f2bf(s[4] * inv) | ((uint_t)f2bf(s[5] * inv) << 16);
    o.w = (uint_t)f2bf(s[6] * inv) | ((uint_t)f2bf(s[7] * inv) << 16);
    *(uint4*)(aggbu + (size_t)i * 64 + l16 * 4) = o;
}

// ---- fused12: layer-1 GEMM + epilogue + layer-2 GEMM, LDS-tiled (R9) ------
// 512 thr = 8 waves; tile = 64 rows; 52KB LDS -> 3 blocks/CU.

__global__ __launch_bounds__(512, 6) void fused12_kernel(
        const ushort_t* __restrict__ xb, const ushort_t* __restrict__ aggb,
        const ushort_t* __restrict__ w1lt, const ushort_t* __restrict__ w1rt,
        const ushort_t* __restrict__ w2lt, const ushort_t* __restrict__ w2rt,
        const float* __restrict__ b1,
        ushort_t* __restrict__ z2b, float* __restrict__ r2, int n) {
    __shared__ ushort_t xs[64 * PSTR];          // x tile; becomes hs after layer 1
    __shared__ ushort_t as_[64 * PSTR];         // agg tile
    __shared__ ushort_t ws2[2 * 32 * PSTR];     // W2l^T | W2r^T

    const int t    = threadIdx.x;
    const int wave = t >> 6;            // 0..7
    const int lane = t & 63;
    const int quad = lane >> 4;
    const int l16  = lane & 15;
    const int row0 = blockIdx.x * 64;
    const int c1   = wave * 16;         // layer-1 col tile

    // stage xb + aggb tiles: 1024 16B chunks each, 2 per thread, coalesced
#pragma unroll
    for (int it = 0; it < 2; it++) {
        int c   = t + it * 512;
        int row = c >> 4, col = c & 15;
        int grow = row0 + row; if (grow >= n) grow = n - 1;   // clamp; stores guarded
        size_t goff = (size_t)grow * FDIM + col * 8;
        short8 vx = *(const short8*)(xb + goff);
        short8 va = *(const short8*)(aggb + goff);
        *(short8*)(xs  + row * PSTR + col * 8) = vx;
        *(short8*)(as_ + row * PSTR + col * 8) = va;
    }
    // stage W2 (both 32x128): 1024 chunks, 2 per thread
#pragma unroll
    for (int it = 0; it < 2; it++) {
        int c = t + it * 512;
        int m = c >> 9, lo = c & 511;
        int row = lo >> 4, col = lo & 15;
        const ushort_t* sw = m ? w2rt : w2lt;
        *(short8*)(ws2 + (m * 32 + row) * PSTR + col * 8) =
            *(const short8*)(sw + row * 128 + col * 8);
    }

    // W1 B-frags for this wave's 16 cols -> registers (L2-resident)
    short8 bl1[4], br1[4];
#pragma unroll
    for (int k = 0; k < 4; k++) {
        size_t woff = (size_t)(c1 + l16) * FDIM + k * 32 + quad * 8;
        bl1[k] = *(const short8*)(w1lt + woff);
        br1[k] = *(const short8*)(w1rt + woff);
    }
    float b1c = b1[c1 + l16];

    __syncthreads();

    // ---- layer 1: A-frags from LDS ----
    f32x4 acc1[4];
#pragma unroll
    for (int r = 0; r < 4; r++) acc1[r] = (f32x4){0.f, 0.f, 0.f, 0.f};

#pragma unroll
    for (int k = 0; k < 4; k++) {
        short8 a1[4], a2[4];
#pragma unroll
        for (int r = 0; r < 4; r++) {
            int lro = (r * 16 + l16) * PSTR + k * 32 + quad * 8;
            a1[r] = *(const short8*)(as_ + lro);
            a2[r] = *(const short8*)(xs  + lro);
        }
#pragma unroll
        for (int r = 0; r < 4; r++) {
            acc1[r] = __builtin_amdgcn_mfma_f32_16x16x32_bf16(a1[r], bl1[k], acc1[r], 0, 0, 0);
            acc1[r] = __builtin_amdgcn_mfma_f32_16x16x32_bf16(a2[r], br1[k], acc1[r], 0, 0, 0);
        }
    }

    __syncthreads();          // all waves done reading xs before hs overwrite

    // epilogue -> hs (= xs). C/D: col = l16, row = quad*4 + reg.
    ushort_t* hs = xs;
#pragma unroll
    for (int r = 0; r < 4; r++)
#pragma unroll
        for (int reg = 0; reg < 4; reg++) {
            int lrow = r * 16 + quad * 4 + reg;
            float v = acc1[r][reg] + b1c;
            v = v > 0.f ? v : 0.f;
            hs[lrow * PSTR + c1 + l16] = f2bf(v);
        }

    __syncthreads();

    // ---- layer 2 ----
    const int rs = (wave >> 1) * 16;    // row sub-tile
    const int c2 = (wave & 1) * 16;     // col tile
    f32x4 a2l = (f32x4){0.f, 0.f, 0.f, 0.f};
    f32x4 a2r = (f32x4){0.f, 0.f, 0.f, 0.f};
#pragma unroll
    for (int k = 0; k < 4; k++) {
        short8 ah = *(const short8*)(hs  + (rs + l16) * PSTR + k * 32 + quad * 8);
        short8 wl = *(const short8*)(ws2 + (c2 + l16) * PSTR + k * 32 + quad * 8);
        short8 wr = *(const short8*)(ws2 + (32 + c2 + l16) * PSTR + k * 32 + quad * 8);
        a2l = __builtin_amdgcn_mfma_f32_16x16x32_bf16(ah, wl, a2l, 0, 0, 0);
        a2r = __builtin_amdgcn_mfma_f32_16x16x32_bf16(ah, wr, a2r, 0, 0, 0);
    }
#pragma unroll
    for (int reg = 0; reg < 4; reg++) {
        int grow = row0 + rs + quad * 4 + reg;
        if (grow < n) {
            z2b[(size_t)grow * CDIM + c2 + l16] = f2bf(a2l[reg]);
            r2 [(size_t)grow * CDIM + c2 + l16] = a2r[reg];
        }
    }
}

// ---- combine2: out = inv * sum_j z2b[j] + r2 + b2 -------------------------
// ONE NODE PER 16-LANE GROUP: lanes partition the 64B row (uint/lane),
// serial 2-deep edge walk, no reduce; float2/lane epilogue.

__global__ __launch_bounds__(256) void combine2_kernel(
        const uint_t* __restrict__ z2bu /* N x 16 uints */,
        const int* __restrict__ rowptr, const int* __restrict__ deg,
        const int* __restrict__ nbr, const float* __restrict__ b2,
        const float* __restrict__ r2, float* __restrict__ out, int n) {
    int t = threadIdx.x;
    int i = blockIdx.x * 16 + (t >> 4);
    if (i >= n) return;
    int l16 = t & 15;
    int start = rowptr[i];
    int d     = deg[i];
    float s0 = 0.f, s1 = 0.f;
    int e = 0;
    for (; e + 1 < d; e += 2) {
        int j0 = nbr[start + e];
        int j1 = nbr[start + e + 1];
        uint_t u0 = z2bu[(size_t)j0 * 16 + l16];
        uint_t u1 = z2bu[(size_t)j1 * 16 + l16];
        s0 += bf2f_lo(u0) + bf2f_lo(u1);
        s1 += bf2f_hi(u0) + bf2f_hi(u1);
    }
    if (e < d) {
        int j = nbr[start + e];
        uint_t u = z2bu[(size_t)j * 16 + l16];
        s0 += bf2f_lo(u);
        s1 += bf2f_hi(u);
    }
    float inv = 1.0f / (float)(d > 0 ? d : 1);
    float2 rr = *(const float2*)(r2 + (size_t)i * CDIM + l16 * 2);
    float2 bb = *(const float2*)(b2 + l16 * 2);
    float2 o;
    o.x = s0 * inv + rr.x + bb.x;
    o.y = s1 * inv + rr.y + bb.y;
    *(float2*)(out + (size_t)i * CDIM + l16 * 2) = o;
}

// ---------------------------------------------------------------------------

extern "C" void kernel_launch(void* const* d_in, const int* in_sizes, int n_in,
                              void* d_out, int out_size, void* d_ws, size_t ws_size,
                              hipStream_t stream) {
    const float* x   = (const float*)d_in[0];
    const int*   ei  = (const int*)d_in[1];     // int64 in ref -> int32 here
    const float* W1l = (const float*)d_in[2];
    const float* b1  = (const float*)d_in[3];
    const float* W1r = (const float*)d_in[4];
    const float* W2l = (const float*)d_in[5];
    const float* b2  = (const float*)d_in[6];
    const float* W2r = (const float*)d_in[7];

    const int N = in_sizes[0] / FDIM;
    const int E = in_sizes[1] / 2;
    const int* src = ei;
    const int* dst = ei + E;

    char* p = (char*)d_ws;
    int*      deg      = (int*)p;      p += (size_t)N * sizeof(int);
    int*      cursor   = (int*)p;      p += (size_t)N * sizeof(int);
    int*      rowptr   = (int*)p;      p += (size_t)N * sizeof(int);
    int*      partials = (int*)p;      p += 256 * sizeof(int);
    ushort_t* w1lt     = (ushort_t*)p; p += FDIM * FDIM * sizeof(ushort_t);
    ushort_t* w1rt     = (ushort_t*)p; p += FDIM * FDIM * sizeof(ushort_t);
    ushort_t* w2lt     = (ushort_t*)p; p += FDIM * CDIM * sizeof(ushort_t);
    ushort_t* w2rt     = (ushort_t*)p; p += FDIM * CDIM * sizeof(ushort_t);
    int*      nbr      = (int*)p;      p += (size_t)((E + 3) / 4 * 4) * sizeof(int);
    ushort_t* xb       = (ushort_t*)p; p += (size_t)N * FDIM * sizeof(ushort_t);
    ushort_t* aggb     = (ushort_t*)p; p += (size_t)N * FDIM * sizeof(ushort_t);
    ushort_t* z2b      = (ushort_t*)p; p += (size_t)N * CDIM * sizeof(ushort_t);
    float*    r2       = (float*)p;    p += (size_t)N * CDIM * sizeof(float);

    const int SB = (N + SCAN_CHUNK - 1) / SCAN_CHUNK;
    const long long total8 = (long long)N * FDIM / 8;
    const int CB = (int)((total8 + 255) / 256);
    const int E4 = (E + 3) / 4;
    const int DB4 = (E4 + 255) / 256;
    const int WB = (40960 + 255) / 256;

    hipMemsetAsync(deg, 0, (size_t)N * sizeof(int), stream);  // cursor seeded by scan3

    prep_kernel <<<DB4 + CB + WB, 256, 0, stream>>>(dst, deg, E, N,
                                                    x, (uint_t*)xb, total8,
                                                    W1l, W1r, W2l, W2r,
                                                    w1lt, w1rt, w2lt, w2rt, DB4, CB);
    scan1_kernel<<<SB, 256, 0, stream>>>(deg, partials, N);
    scan3_kernel<<<SB, 256, 0, stream>>>(deg, partials, rowptr, cursor, N, SB);
    fill_kernel <<<DB4, 256, 0, stream>>>(src, dst, cursor, nbr, E, N);

    agg1_kernel   <<<(N + 15) / 16, 256, 0, stream>>>((const uint_t*)xb, rowptr, deg, nbr,
                                                      (uint_t*)aggb, N);
    fused12_kernel<<<(N + 63) / 64, 512, 0, stream>>>(xb, aggb, w1lt, w1rt, w2lt, w2rt,
                                                      b1, z2b, r2, N);
    combine2_kernel<<<(N + 15) / 16, 256, 0, stream>>>((const uint_t*)z2b, rowptr, deg, nbr,
                                                       b2, r2, (float*)d_out, N);
}